// Round 1
// baseline (1231.480 us; speedup 1.0000x reference)
//
#include <hip/hip_runtime.h>

#define TPB 256

// ---------------- degree / norm ----------------

__global__ void k_deg(const int* __restrict__ dst, unsigned* __restrict__ deg, int E) {
    int e = blockIdx.x * TPB + threadIdx.x;
    if (e < E) atomicAdd(&deg[dst[e]], 1u);
}

__global__ void k_dinv(const unsigned* __restrict__ deg, float* __restrict__ dinv, int N) {
    int i = blockIdx.x * TPB + threadIdx.x;
    if (i < N) dinv[i] = rsqrtf((float)(deg[i] + 1u));   // +1 = self-loop
}

// ---------------- layer 1: lin 3->64, fused dinv scale, writes g and agg(self-loop init)

__global__ void k_lin3(const float* __restrict__ x, const float* __restrict__ W,
                       const float* __restrict__ dinv,
                       float* __restrict__ g, float* __restrict__ agg, int N) {
    int tid = blockIdx.x * TPB + threadIdx.x;
    int node = tid >> 6, f = tid & 63;
    if (node >= N) return;
    float v = x[node*3+0] * W[f] + x[node*3+1] * W[64+f] + x[node*3+2] * W[128+f];
    v *= dinv[node];
    g[tid] = v;
    agg[tid] = v;
}

// ---------------- lin 64->64 (wave holds one node row; shuffle-broadcast) ----

__global__ void k_lin64(const float* __restrict__ h, const float* __restrict__ W,
                        const float* __restrict__ dinv,
                        float* __restrict__ g, float* __restrict__ agg, int N) {
    __shared__ float Ws[4096];
    for (int i = threadIdx.x; i < 4096; i += TPB) Ws[i] = W[i];
    __syncthreads();
    int tid = blockIdx.x * TPB + threadIdx.x;
    int node = tid >> 6, f = tid & 63;
    if (node >= N) return;          // N*64 is an exact multiple of TPB; waves stay full
    float xv = h[tid];              // h[node*64 + f], coalesced
    float acc = 0.f;
#pragma unroll
    for (int k = 0; k < 64; ++k)
        acc = fmaf(__shfl(xv, k, 64), Ws[(k << 6) + f], acc);
    acc *= dinv[node];
    g[tid] = acc;
    agg[tid] = acc;
}

// ---------------- lin 64->3 (wave-per-node shuffle reduction) ----------------

__global__ void k_lin64_3(const float* __restrict__ h, const float* __restrict__ W,
                          const float* __restrict__ dinv,
                          float* __restrict__ g, float* __restrict__ agg, int N) {
    int tid = blockIdx.x * TPB + threadIdx.x;
    int node = tid >> 6, k = tid & 63;
    if (node >= N) return;
    float hv = h[tid];
    float a0 = hv * W[k*3+0];
    float a1 = hv * W[k*3+1];
    float a2 = hv * W[k*3+2];
#pragma unroll
    for (int off = 32; off > 0; off >>= 1) {
        a0 += __shfl_down(a0, off, 64);
        a1 += __shfl_down(a1, off, 64);
        a2 += __shfl_down(a2, off, 64);
    }
    if (k == 0) {
        float dv = dinv[node];
        float v0 = a0 * dv, v1 = a1 * dv, v2 = a2 * dv;
        g[node*3+0] = v0;  agg[node*3+0] = v0;
        g[node*3+1] = v1;  agg[node*3+1] = v1;
        g[node*3+2] = v2;  agg[node*3+2] = v2;
    }
}

// ---------------- edge scatter-add ----------------

__global__ void k_scatter64(const int* __restrict__ src, const int* __restrict__ dst,
                            const float* __restrict__ g, float* __restrict__ agg, int E) {
    int tid = blockIdx.x * TPB + threadIdx.x;
    int e = tid >> 6, f = tid & 63;
    if (e >= E) return;
    int s = src[e], d = dst[e];                 // wave-uniform -> L1 broadcast
    atomicAdd(&agg[((long long)d << 6) + f], g[((long long)s << 6) + f]);
}

__global__ void k_scatter3(const int* __restrict__ src, const int* __restrict__ dst,
                           const float* __restrict__ g, float* __restrict__ agg, int E) {
    int e = blockIdx.x * TPB + threadIdx.x;
    if (e >= E) return;
    int s = src[e], d = dst[e];
    atomicAdd(&agg[d*3+0], g[s*3+0]);
    atomicAdd(&agg[d*3+1], g[s*3+1]);
    atomicAdd(&agg[d*3+2], g[s*3+2]);
}

// ---------------- finalize: out = dinv*agg + b (opt relu) ----------------

__global__ void k_fin64(const float* __restrict__ agg, const float* __restrict__ dinv,
                        const float* __restrict__ b, float* __restrict__ out,
                        int N, int relu) {
    int tid = blockIdx.x * TPB + threadIdx.x;
    int node = tid >> 6, f = tid & 63;
    if (node >= N) return;
    float v = agg[tid] * dinv[node] + b[f];
    if (relu) v = fmaxf(v, 0.f);
    out[tid] = v;
}

__global__ void k_fin3(const float* __restrict__ agg, const float* __restrict__ dinv,
                       const float* __restrict__ b, float* __restrict__ out, int N) {
    int tid = blockIdx.x * TPB + threadIdx.x;
    if (tid >= N * 3) return;
    int node = tid / 3;
    int c = tid - node * 3;
    out[tid] = agg[tid] * dinv[node] + b[c];
}

extern "C" void kernel_launch(void* const* d_in, const int* in_sizes, int n_in,
                              void* d_out, int out_size, void* d_ws, size_t ws_size,
                              hipStream_t stream) {
    const float* x  = (const float*)d_in[0];
    const int*   ei = (const int*)  d_in[1];
    const float* W1 = (const float*)d_in[2];
    const float* b1 = (const float*)d_in[3];
    const float* W2 = (const float*)d_in[4];
    const float* b2 = (const float*)d_in[5];
    const float* W3 = (const float*)d_in[6];
    const float* b3 = (const float*)d_in[7];
    float* out = (float*)d_out;

    const int N = in_sizes[0] / 3;       // 100000
    const int E = in_sizes[1] / 2;       // 1600000
    const int* srcI = ei;
    const int* dstI = ei + E;

    // workspace layout (floats): dinv | deg | g | agg | h
    float*    ws   = (float*)d_ws;
    float*    dinv = ws;                                   // N
    unsigned* deg  = (unsigned*)(ws + 131072);             // N
    float*    g    = ws + 262144;                          // N*64
    float*    agg  = g   + (size_t)N * 64;                 // N*64
    float*    h    = agg + (size_t)N * 64;                 // N*64

    hipMemsetAsync(deg, 0, (size_t)N * sizeof(unsigned), stream);

    int gE   = (E + TPB - 1) / TPB;
    int gN   = (N + TPB - 1) / TPB;
    int gN64 = ((size_t)N * 64 + TPB - 1) / TPB;
    int gE64 = (int)(((size_t)E * 64 + TPB - 1) / TPB);
    int gN3  = ((size_t)N * 3 + TPB - 1) / TPB;

    k_deg <<<gE, TPB, 0, stream>>>(dstI, deg, E);
    k_dinv<<<gN, TPB, 0, stream>>>(deg, dinv, N);

    // layer 1: 3 -> 64, relu
    k_lin3     <<<gN64, TPB, 0, stream>>>(x, W1, dinv, g, agg, N);
    k_scatter64<<<gE64, TPB, 0, stream>>>(srcI, dstI, g, agg, E);
    k_fin64    <<<gN64, TPB, 0, stream>>>(agg, dinv, b1, h, N, 1);

    // layer 2: 64 -> 64, relu
    k_lin64    <<<gN64, TPB, 0, stream>>>(h, W2, dinv, g, agg, N);
    k_scatter64<<<gE64, TPB, 0, stream>>>(srcI, dstI, g, agg, E);
    k_fin64    <<<gN64, TPB, 0, stream>>>(agg, dinv, b2, h, N, 1);

    // layer 3: 64 -> 3, no relu
    k_lin64_3  <<<gN64, TPB, 0, stream>>>(h, W3, dinv, g, agg, N);
    k_scatter3 <<<gE,   TPB, 0, stream>>>(srcI, dstI, g, agg, E);
    k_fin3     <<<gN3,  TPB, 0, stream>>>(agg, dinv, b3, out, N);
}

// Round 2
// 542.500 us; speedup vs baseline: 2.2700x; 2.2700x over previous
//
#include <hip/hip_runtime.h>

#define TPB 256

// ---------------- degree / norm ----------------

__global__ void k_deg(const int* __restrict__ dst, unsigned* __restrict__ deg, int E) {
    int e = blockIdx.x * TPB + threadIdx.x;
    if (e < E) atomicAdd(&deg[dst[e]], 1u);
}

__global__ void k_dinv(const unsigned* __restrict__ deg, float* __restrict__ dinv, int N) {
    int i = blockIdx.x * TPB + threadIdx.x;
    if (i < N) dinv[i] = rsqrtf((float)(deg[i] + 1u));   // +1 = self-loop
}

// ---------------- CSR build: exclusive scan of deg -> row_ptr ----------------

__global__ void k_scan_block(const unsigned* __restrict__ deg, int* __restrict__ row_ptr,
                             unsigned* __restrict__ bsum, int N) {
    __shared__ unsigned s[TPB];
    int i = blockIdx.x * TPB + threadIdx.x;
    unsigned v = (i < N) ? deg[i] : 0u;
    s[threadIdx.x] = v;
    __syncthreads();
#pragma unroll
    for (int o = 1; o < TPB; o <<= 1) {
        unsigned t = (threadIdx.x >= o) ? s[threadIdx.x - o] : 0u;
        __syncthreads();
        s[threadIdx.x] += t;
        __syncthreads();
    }
    if (i < N) row_ptr[i] = (int)(s[threadIdx.x] - v);       // exclusive within block
    if (threadIdx.x == TPB - 1) bsum[blockIdx.x] = s[TPB - 1];
}

__global__ void k_scan_bsum(unsigned* __restrict__ bsum, int NB) {
    __shared__ unsigned s[512];
    int t = threadIdx.x;
    unsigned orig = (t < NB) ? bsum[t] : 0u;
    s[t] = orig;
    __syncthreads();
#pragma unroll
    for (int o = 1; o < 512; o <<= 1) {
        unsigned v = (t >= o) ? s[t - o] : 0u;
        __syncthreads();
        s[t] += v;
        __syncthreads();
    }
    if (t < NB) bsum[t] = s[t] - orig;                        // exclusive block offsets
}

__global__ void k_add_off(int* __restrict__ row_ptr, const unsigned* __restrict__ bsum,
                          int N, int E) {
    int i = blockIdx.x * TPB + threadIdx.x;
    if (i < N) row_ptr[i] += (int)bsum[blockIdx.x];
    if (i == 0) row_ptr[N] = E;
}

__global__ void k_place(const int* __restrict__ src, const int* __restrict__ dst,
                        const int* __restrict__ row_ptr, unsigned* __restrict__ cursor,
                        int* __restrict__ sorted_src, int E) {
    int e = blockIdx.x * TPB + threadIdx.x;
    if (e >= E) return;
    int d = dst[e];
    unsigned ofs = atomicAdd(&cursor[d], 1u);
    sorted_src[row_ptr[d] + (int)ofs] = src[e];
}

// ---------------- layer 1: lin 3->64, fused dinv scale ----------------

__global__ void k_lin3(const float* __restrict__ x, const float* __restrict__ W,
                       const float* __restrict__ dinv, float* __restrict__ g, int N) {
    int tid = blockIdx.x * TPB + threadIdx.x;
    int node = tid >> 6, f = tid & 63;
    if (node >= N) return;
    float v = x[node*3+0] * W[f] + x[node*3+1] * W[64+f] + x[node*3+2] * W[128+f];
    g[tid] = v * dinv[node];
}

// ---------------- lin 64->64 (wave holds one node row; shuffle-broadcast) ----

__global__ void k_lin64(const float* __restrict__ h, const float* __restrict__ W,
                        const float* __restrict__ dinv, float* __restrict__ g, int N) {
    __shared__ float Ws[4096];
    for (int i = threadIdx.x; i < 4096; i += TPB) Ws[i] = W[i];
    __syncthreads();
    int tid = blockIdx.x * TPB + threadIdx.x;
    int node = tid >> 6, f = tid & 63;
    if (node >= N) return;
    float xv = h[tid];
    float acc = 0.f;
#pragma unroll
    for (int k = 0; k < 64; ++k)
        acc = fmaf(__shfl(xv, k, 64), Ws[(k << 6) + f], acc);
    g[tid] = acc * dinv[node];
}

// ---------------- lin 64->3 (wave-per-node shuffle reduction) ----------------

__global__ void k_lin64_3(const float* __restrict__ h, const float* __restrict__ W,
                          const float* __restrict__ dinv, float* __restrict__ g, int N) {
    int tid = blockIdx.x * TPB + threadIdx.x;
    int node = tid >> 6, k = tid & 63;
    if (node >= N) return;
    float hv = h[tid];
    float a0 = hv * W[k*3+0];
    float a1 = hv * W[k*3+1];
    float a2 = hv * W[k*3+2];
#pragma unroll
    for (int off = 32; off > 0; off >>= 1) {
        a0 += __shfl_down(a0, off, 64);
        a1 += __shfl_down(a1, off, 64);
        a2 += __shfl_down(a2, off, 64);
    }
    if (k == 0) {
        float dv = dinv[node];
        g[node*3+0] = a0 * dv;
        g[node*3+1] = a1 * dv;
        g[node*3+2] = a2 * dv;
    }
}

// ---------------- pull aggregation (CSR), fused finalize ----------------
// out[node,f] = relu?( dinv[node] * (g[node,f] + sum_{s in nbrs} g[s,f]) + b[f] )

__global__ void k_pull64(const float* __restrict__ g, const int* __restrict__ row_ptr,
                         const int* __restrict__ srcs, const float* __restrict__ dinv,
                         const float* __restrict__ b, float* __restrict__ out,
                         int N, int relu) {
    int tid = blockIdx.x * TPB + threadIdx.x;
    int node = tid >> 6, f = tid & 63;
    if (node >= N) return;
    int beg = row_ptr[node], end = row_ptr[node + 1];
    float acc = g[tid];                         // self-loop
    int j = beg;
    for (; j + 3 < end; j += 4) {               // 4 independent gathers in flight
        int s0 = srcs[j], s1 = srcs[j+1], s2 = srcs[j+2], s3 = srcs[j+3];
        float v0 = g[(s0 << 6) + f];
        float v1 = g[(s1 << 6) + f];
        float v2 = g[(s2 << 6) + f];
        float v3 = g[(s3 << 6) + f];
        acc += (v0 + v1) + (v2 + v3);
    }
    for (; j < end; ++j) acc += g[(srcs[j] << 6) + f];
    float v = acc * dinv[node] + b[f];
    if (relu) v = fmaxf(v, 0.f);
    out[tid] = v;
}

__global__ void k_pull3(const float* __restrict__ g, const int* __restrict__ row_ptr,
                        const int* __restrict__ srcs, const float* __restrict__ dinv,
                        const float* __restrict__ b, float* __restrict__ out, int N) {
    int node = blockIdx.x * TPB + threadIdx.x;
    if (node >= N) return;
    float a0 = g[node*3+0], a1 = g[node*3+1], a2 = g[node*3+2];
    int beg = row_ptr[node], end = row_ptr[node + 1];
    for (int j = beg; j < end; ++j) {
        int s = srcs[j];
        a0 += g[s*3+0];
        a1 += g[s*3+1];
        a2 += g[s*3+2];
    }
    float dv = dinv[node];
    out[node*3+0] = a0 * dv + b[0];
    out[node*3+1] = a1 * dv + b[1];
    out[node*3+2] = a2 * dv + b[2];
}

extern "C" void kernel_launch(void* const* d_in, const int* in_sizes, int n_in,
                              void* d_out, int out_size, void* d_ws, size_t ws_size,
                              hipStream_t stream) {
    const float* x  = (const float*)d_in[0];
    const int*   ei = (const int*)  d_in[1];
    const float* W1 = (const float*)d_in[2];
    const float* b1 = (const float*)d_in[3];
    const float* W2 = (const float*)d_in[4];
    const float* b2 = (const float*)d_in[5];
    const float* W3 = (const float*)d_in[6];
    const float* b3 = (const float*)d_in[7];
    float* out = (float*)d_out;

    const int N = in_sizes[0] / 3;       // 100000
    const int E = in_sizes[1] / 2;       // 1600000
    const int* srcI = ei;
    const int* dstI = ei + E;

    // workspace layout (floats):
    // dinv(128K) | deg(128K) | cursor(128K) | row_ptr(128K) | bsum(1K) | sorted_src(E) | g(N*64) | h(N*64)
    float*    ws       = (float*)d_ws;
    float*    dinv     = ws;                                 // N
    unsigned* deg      = (unsigned*)(ws + 131072);           // N
    unsigned* cursor   = (unsigned*)(ws + 262144);           // N
    int*      row_ptr  = (int*)     (ws + 393216);           // N+1
    unsigned* bsum     = (unsigned*)(ws + 524288);           // <=512
    int*      sorted_src = (int*)   (ws + 525312);           // E
    float*    g        = ws + 525312 + (size_t)E;            // N*64
    float*    h        = g + (size_t)N * 64;                 // N*64

    hipMemsetAsync(deg,    0, (size_t)N * sizeof(unsigned), stream);
    hipMemsetAsync(cursor, 0, (size_t)N * sizeof(unsigned), stream);

    int gE   = (E + TPB - 1) / TPB;
    int gN   = (N + TPB - 1) / TPB;          // also the scan grid (391 blocks)
    int gN64 = (int)(((size_t)N * 64 + TPB - 1) / TPB);

    // graph preprocessing (once; reused by all 3 layers)
    k_deg       <<<gE, TPB, 0, stream>>>(dstI, deg, E);
    k_dinv      <<<gN, TPB, 0, stream>>>(deg, dinv, N);
    k_scan_block<<<gN, TPB, 0, stream>>>(deg, row_ptr, bsum, N);
    k_scan_bsum <<<1, 512, 0, stream>>>(bsum, gN);
    k_add_off   <<<gN, TPB, 0, stream>>>(row_ptr, bsum, N, E);
    k_place     <<<gE, TPB, 0, stream>>>(srcI, dstI, row_ptr, cursor, sorted_src, E);

    // layer 1: 3 -> 64, relu
    k_lin3  <<<gN64, TPB, 0, stream>>>(x, W1, dinv, g, N);
    k_pull64<<<gN64, TPB, 0, stream>>>(g, row_ptr, sorted_src, dinv, b1, h, N, 1);

    // layer 2: 64 -> 64, relu
    k_lin64 <<<gN64, TPB, 0, stream>>>(h, W2, dinv, g, N);
    k_pull64<<<gN64, TPB, 0, stream>>>(g, row_ptr, sorted_src, dinv, b2, h, N, 1);

    // layer 3: 64 -> 3, no relu
    k_lin64_3<<<gN64, TPB, 0, stream>>>(h, W3, dinv, g, N);
    k_pull3  <<<gN,   TPB, 0, stream>>>(g, row_ptr, sorted_src, dinv, b3, out, N);
}